// Round 1
// baseline (1055.699 us; speedup 1.0000x reference)
//
#include <hip/hip_runtime.h>
#include <hip/hip_bf16.h>

#define D 128
#define LDSPAD 136  // 128 + 8 bf16 pad -> 2-way LDS bank aliasing (free)

typedef short s8v __attribute__((ext_vector_type(8)));  // 8 bf16 = 4 VGPRs
typedef float f4v __attribute__((ext_vector_type(4)));  // 4 f32 accum

__device__ inline short f2bf(float f) {
    __hip_bfloat16 h = __float2bfloat16(f);  // RNE
    return *reinterpret_cast<short*>(&h);
}

// Convert 128x128 f32 W (row-major) into LDS bf16 with padded stride.
// Requires blockDim.x == 256.
__device__ inline void load_w_lds(const float* __restrict__ W, short* lds) {
    const int tid = threadIdx.x;
    const float4* W4 = reinterpret_cast<const float4*>(W);
#pragma unroll
    for (int i = 0; i < 16; ++i) {
        int f = tid + 256 * i;          // 0..4095 float4s
        float4 v = W4[f];
        int row = f >> 5;               // /32 float4s per row
        int c4  = (f & 31) * 4;
        short* p = &lds[row * LDSPAD + c4];
        p[0] = f2bf(v.x); p[1] = f2bf(v.y);
        p[2] = f2bf(v.z); p[3] = f2bf(v.w);
    }
}

// One wave computes a 16x128 tile of X @ W^T via 8 col-tiles x 4 k-chunks
// of v_mfma_f32_16x16x32_bf16. X is f32 [rows][128]; W is bf16 in LDS.
__device__ inline void mfma_tile(const float* __restrict__ X, int row0,
                                 const short* lds, f4v acc[8]) {
    const int lane = threadIdx.x & 63;
    const int l15 = lane & 15, q = lane >> 4;
    s8v a[4];
    const float* xr = X + (size_t)(row0 + l15) * D + q * 8;
#pragma unroll
    for (int c = 0; c < 4; ++c) {
        float4 f0 = *reinterpret_cast<const float4*>(xr + c * 32);
        float4 f1 = *reinterpret_cast<const float4*>(xr + c * 32 + 4);
        s8v t;
        t[0] = f2bf(f0.x); t[1] = f2bf(f0.y); t[2] = f2bf(f0.z); t[3] = f2bf(f0.w);
        t[4] = f2bf(f1.x); t[5] = f2bf(f1.y); t[6] = f2bf(f1.z); t[7] = f2bf(f1.w);
        a[c] = t;
    }
#pragma unroll
    for (int t = 0; t < 8; ++t) {
        f4v acc_t = {0.f, 0.f, 0.f, 0.f};
#pragma unroll
        for (int c = 0; c < 4; ++c) {
            const s8v b = *reinterpret_cast<const s8v*>(
                &lds[(t * 16 + l15) * LDSPAD + c * 32 + q * 8]);
            acc_t = __builtin_amdgcn_mfma_f32_16x16x32_bf16(a[c], b, acc_t, 0, 0, 0);
        }
        acc[t] = acc_t;
    }
}

__global__ __launch_bounds__(256) void k_zero(float4* p, int n4) {
    int i = blockIdx.x * 256 + threadIdx.x;
    if (i < n4) p[i] = float4{0.f, 0.f, 0.f, 0.f};
}

// P = X @ W^T   (X: [nrows,128] f32, W: [128,128] f32, P: [nrows,128] f32)
__global__ __launch_bounds__(256) void k_node_gemm(const float* __restrict__ X,
                                                   const float* __restrict__ W,
                                                   float* __restrict__ P, int nrows) {
    __shared__ short lds[D * LDSPAD];
    load_w_lds(W, lds);
    __syncthreads();
    const int lane = threadIdx.x & 63, wave = threadIdx.x >> 6;
    const int l15 = lane & 15, q = lane >> 4;
    const int ntiles = nrows >> 4;
    for (int tile = blockIdx.x * 4 + wave; tile < ntiles; tile += gridDim.x * 4) {
        f4v acc[8];
        mfma_tile(X, tile * 16, lds, acc);
#pragma unroll
        for (int t = 0; t < 8; ++t) {
            int col = t * 16 + l15;
#pragma unroll
            for (int r = 0; r < 4; ++r)
                P[(size_t)(tile * 16 + q * 4 + r) * D + col] = acc[t][r];
        }
    }
}

// Per-edge: msg = edge@We2e^T + Ps[sidx] + Pt[tidx]; e_out = edge + LN(silu(msg));
// write e_out; atomicAdd into agg[tidx].
__global__ __launch_bounds__(256) void k_edge(const float* __restrict__ edge,
                                              const int* __restrict__ sidx,
                                              const int* __restrict__ tidx,
                                              const float* __restrict__ W,
                                              const float* __restrict__ Ps,
                                              const float* __restrict__ Pt,
                                              const float* __restrict__ g1,
                                              const float* __restrict__ b1,
                                              float* __restrict__ eout,
                                              float* __restrict__ agg, int E) {
    __shared__ short lds[D * LDSPAD];
    load_w_lds(W, lds);
    __syncthreads();
    const int lane = threadIdx.x & 63, wave = threadIdx.x >> 6;
    const int l15 = lane & 15, q = lane >> 4;
    const int ntiles = E >> 4;
    for (int tile = blockIdx.x * 4 + wave; tile < ntiles; tile += gridDim.x * 4) {
        const int e0 = tile * 16;
        f4v acc[8];
        mfma_tile(edge, e0, lds, acc);
        int si[4], ti[4];
#pragma unroll
        for (int r = 0; r < 4; ++r) {
            si[r] = sidx[e0 + q * 4 + r];
            ti[r] = tidx[e0 + q * 4 + r];
        }
        float h[8][4];
        float s1[4] = {0.f, 0.f, 0.f, 0.f}, s2[4] = {0.f, 0.f, 0.f, 0.f};
#pragma unroll
        for (int t = 0; t < 8; ++t) {
            int col = t * 16 + l15;
#pragma unroll
            for (int r = 0; r < 4; ++r) {
                float m = acc[t][r] + Ps[(size_t)si[r] * D + col]
                                    + Pt[(size_t)ti[r] * D + col];
                float hh = m / (1.f + __expf(-m));   // silu
                h[t][r] = hh;
                s1[r] += hh;
                s2[r] += hh * hh;
            }
        }
#pragma unroll
        for (int m = 1; m < 16; m <<= 1) {
#pragma unroll
            for (int r = 0; r < 4; ++r) {
                s1[r] += __shfl_xor(s1[r], m, 64);
                s2[r] += __shfl_xor(s2[r], m, 64);
            }
        }
        float mean[4], rstd[4];
#pragma unroll
        for (int r = 0; r < 4; ++r) {
            float mu = s1[r] * (1.f / 128.f);
            float var = s2[r] * (1.f / 128.f) - mu * mu;
            mean[r] = mu;
            rstd[r] = rsqrtf(var + 1e-5f);
        }
#pragma unroll
        for (int t = 0; t < 8; ++t) {
            int col = t * 16 + l15;
            float gg = g1[col], bb = b1[col];
#pragma unroll
            for (int r = 0; r < 4; ++r) {
                int rowg = e0 + q * 4 + r;
                float v = edge[(size_t)rowg * D + col]
                          + ((h[t][r] - mean[r]) * rstd[r] * gg + bb);
                eout[(size_t)rowg * D + col] = v;
                atomicAdd(&agg[(size_t)ti[r] * D + col], v);
            }
        }
    }
}

// tgt_msg = agg@We2t^T + Ptt; tgt_out = tgt + LN(silu(tgt_msg)).
// out == aggIn (in-place): each wave reads its 16 rows fully before writing.
__global__ __launch_bounds__(256) void k_node_update(const float* __restrict__ aggIn,
                                                     const float* __restrict__ W,
                                                     const float* __restrict__ Ptt,
                                                     const float* __restrict__ tgt,
                                                     const float* __restrict__ g2,
                                                     const float* __restrict__ b2,
                                                     float* __restrict__ out, int N) {
    __shared__ short lds[D * LDSPAD];
    load_w_lds(W, lds);
    __syncthreads();
    const int lane = threadIdx.x & 63, wave = threadIdx.x >> 6;
    const int l15 = lane & 15, q = lane >> 4;
    const int ntiles = N >> 4;
    for (int tile = blockIdx.x * 4 + wave; tile < ntiles; tile += gridDim.x * 4) {
        const int n0 = tile * 16;
        f4v acc[8];
        mfma_tile(aggIn, n0, lds, acc);
        float h[8][4];
        float s1[4] = {0.f, 0.f, 0.f, 0.f}, s2[4] = {0.f, 0.f, 0.f, 0.f};
#pragma unroll
        for (int t = 0; t < 8; ++t) {
            int col = t * 16 + l15;
#pragma unroll
            for (int r = 0; r < 4; ++r) {
                int rowg = n0 + q * 4 + r;
                float m = acc[t][r] + Ptt[(size_t)rowg * D + col];
                float hh = m / (1.f + __expf(-m));
                h[t][r] = hh;
                s1[r] += hh;
                s2[r] += hh * hh;
            }
        }
#pragma unroll
        for (int m = 1; m < 16; m <<= 1) {
#pragma unroll
            for (int r = 0; r < 4; ++r) {
                s1[r] += __shfl_xor(s1[r], m, 64);
                s2[r] += __shfl_xor(s2[r], m, 64);
            }
        }
        float mean[4], rstd[4];
#pragma unroll
        for (int r = 0; r < 4; ++r) {
            float mu = s1[r] * (1.f / 128.f);
            float var = s2[r] * (1.f / 128.f) - mu * mu;
            mean[r] = mu;
            rstd[r] = rsqrtf(var + 1e-5f);
        }
#pragma unroll
        for (int t = 0; t < 8; ++t) {
            int col = t * 16 + l15;
            float gg = g2[col], bb = b2[col];
#pragma unroll
            for (int r = 0; r < 4; ++r) {
                int rowg = n0 + q * 4 + r;
                float v = tgt[(size_t)rowg * D + col]
                          + ((h[t][r] - mean[r]) * rstd[r] * gg + bb);
                out[(size_t)rowg * D + col] = v;
            }
        }
    }
}

extern "C" void kernel_launch(void* const* d_in, const int* in_sizes, int n_in,
                              void* d_out, int out_size, void* d_ws, size_t ws_size,
                              hipStream_t stream) {
    const float* src   = (const float*)d_in[0];
    const float* tgt   = (const float*)d_in[1];
    const float* edge  = (const float*)d_in[2];
    const int*   sidx  = (const int*)d_in[3];
    const int*   tidx  = (const int*)d_in[4];
    const float* W_s2e = (const float*)d_in[5];
    const float* W_t2e = (const float*)d_in[6];
    const float* W_e2e = (const float*)d_in[7];
    const float* W_e2t = (const float*)d_in[8];
    const float* W_t2t = (const float*)d_in[9];
    const float* g1    = (const float*)d_in[10];
    const float* b1    = (const float*)d_in[11];
    const float* g2    = (const float*)d_in[12];
    const float* b2    = (const float*)d_in[13];

    const int N = in_sizes[0] / D;   // 50000
    const int E = in_sizes[2] / D;   // 500000

    float* eout = (float*)d_out;                    // [E,128]
    float* nout = eout + (size_t)E * D;             // [N,128]: agg, then tgt_out in place

    float* Ps  = (float*)d_ws;                      // [N,128] f32
    float* Pt  = Ps + (size_t)N * D;
    float* Ptt = Pt + (size_t)N * D;

    // zero the agg region (harness poisons d_out)
    {
        int n4 = (N * D) / 4;
        k_zero<<<(n4 + 255) / 256, 256, 0, stream>>>((float4*)nout, n4);
    }

    const int nodeBlocks = (N / 16 + 3) / 4;        // 782: one 16-row tile per wave
    k_node_gemm<<<nodeBlocks, 256, 0, stream>>>(src, W_s2e, Ps, N);
    k_node_gemm<<<nodeBlocks, 256, 0, stream>>>(tgt, W_t2e, Pt, N);
    k_node_gemm<<<nodeBlocks, 256, 0, stream>>>(tgt, W_t2t, Ptt, N);

    k_edge<<<1024, 256, 0, stream>>>(edge, sidx, tidx, W_e2e, Ps, Pt, g1, b1,
                                     eout, nout, E);

    k_node_update<<<nodeBlocks, 256, 0, stream>>>(nout, W_e2t, Ptt, tgt, g2, b2,
                                                  nout, N);
}

// Round 2
// 915.290 us; speedup vs baseline: 1.1534x; 1.1534x over previous
//
#include <hip/hip_runtime.h>
#include <hip/hip_bf16.h>

#define D 128
#define LDSPAD 136  // 128 + 8 bf16 pad -> 2-way LDS bank aliasing (free)

typedef short s8v __attribute__((ext_vector_type(8)));  // 8 bf16 = 4 VGPRs
typedef float f4v __attribute__((ext_vector_type(4)));  // 4 f32 accum

__device__ inline short f2bf(float f) {
    __hip_bfloat16 h = __float2bfloat16(f);  // RNE
    return *reinterpret_cast<short*>(&h);
}

// Convert 128x128 f32 W (row-major) into LDS bf16 with padded stride.
// Requires blockDim.x == 256.
__device__ inline void load_w_lds(const float* __restrict__ W, short* lds) {
    const int tid = threadIdx.x;
    const float4* W4 = reinterpret_cast<const float4*>(W);
#pragma unroll
    for (int i = 0; i < 16; ++i) {
        int f = tid + 256 * i;          // 0..4095 float4s
        float4 v = W4[f];
        int row = f >> 5;               // /32 float4s per row
        int c4  = (f & 31) * 4;
        short* p = &lds[row * LDSPAD + c4];
        p[0] = f2bf(v.x); p[1] = f2bf(v.y);
        p[2] = f2bf(v.z); p[3] = f2bf(v.w);
    }
}

// One wave computes a 16x128 tile of X @ W^T via 8 col-tiles x 4 k-chunks
// of v_mfma_f32_16x16x32_bf16. X is f32 [rows][128]; W is bf16 in LDS.
__device__ inline void mfma_tile(const float* __restrict__ X, int row0,
                                 const short* lds, f4v acc[8]) {
    const int lane = threadIdx.x & 63;
    const int l15 = lane & 15, q = lane >> 4;
    s8v a[4];
    const float* xr = X + (size_t)(row0 + l15) * D + q * 8;
#pragma unroll
    for (int c = 0; c < 4; ++c) {
        float4 f0 = *reinterpret_cast<const float4*>(xr + c * 32);
        float4 f1 = *reinterpret_cast<const float4*>(xr + c * 32 + 4);
        s8v t;
        t[0] = f2bf(f0.x); t[1] = f2bf(f0.y); t[2] = f2bf(f0.z); t[3] = f2bf(f0.w);
        t[4] = f2bf(f1.x); t[5] = f2bf(f1.y); t[6] = f2bf(f1.z); t[7] = f2bf(f1.w);
        a[c] = t;
    }
#pragma unroll
    for (int t = 0; t < 8; ++t) {
        f4v acc_t = {0.f, 0.f, 0.f, 0.f};
#pragma unroll
        for (int c = 0; c < 4; ++c) {
            const s8v b = *reinterpret_cast<const s8v*>(
                &lds[(t * 16 + l15) * LDSPAD + c * 32 + q * 8]);
            acc_t = __builtin_amdgcn_mfma_f32_16x16x32_bf16(a[c], b, acc_t, 0, 0, 0);
        }
        acc[t] = acc_t;
    }
}

// ---------------- CSR build ----------------

__global__ __launch_bounds__(256) void k_zero_i(int* p, int n) {
    int i = blockIdx.x * 256 + threadIdx.x;
    if (i < n) p[i] = 0;
}

__global__ __launch_bounds__(256) void k_hist(const int* __restrict__ tidx,
                                              int* __restrict__ cnt, int E) {
    int i = blockIdx.x * 256 + threadIdx.x;
    if (i < E) atomicAdd(&cnt[tidx[i]], 1);
}

// Exclusive scan of cnt[0..n) -> off[0..n]; also copy to cursor. One block.
__global__ __launch_bounds__(1024) void k_scan(const int* __restrict__ cnt,
                                               int* __restrict__ off,
                                               int* __restrict__ cursor, int n) {
    __shared__ int part[1024];
    const int tid = threadIdx.x;
    const int chunk = (n + 1023) / 1024;
    const int lo = tid * chunk;
    const int hi = min(lo + chunk, n);
    int s = 0;
    for (int i = lo; i < hi; ++i) s += cnt[i];
    part[tid] = s;
    __syncthreads();
    for (int d = 1; d < 1024; d <<= 1) {
        int v = (tid >= d) ? part[tid - d] : 0;
        __syncthreads();
        part[tid] += v;
        __syncthreads();
    }
    int run = part[tid] - s;  // exclusive base for this thread's chunk
    for (int i = lo; i < hi; ++i) {
        off[i] = run;
        cursor[i] = run;
        run += cnt[i];
    }
    if (tid == 0) off[n] = part[1023];
}

__global__ __launch_bounds__(256) void k_scatter(const int* __restrict__ tidx,
                                                 int* __restrict__ cursor,
                                                 int* __restrict__ elist, int E) {
    int i = blockIdx.x * 256 + threadIdx.x;
    if (i < E) {
        int p = atomicAdd(&cursor[tidx[i]], 1);
        elist[p] = i;
    }
}

// ---------------- GEMM kernels ----------------

// P = X @ W^T   (X: [nrows,128] f32, W: [128,128] f32, P: [nrows,128] f32)
__global__ __launch_bounds__(256) void k_node_gemm(const float* __restrict__ X,
                                                   const float* __restrict__ W,
                                                   float* __restrict__ P, int nrows) {
    __shared__ short lds[D * LDSPAD];
    load_w_lds(W, lds);
    __syncthreads();
    const int lane = threadIdx.x & 63, wave = threadIdx.x >> 6;
    const int l15 = lane & 15, q = lane >> 4;
    const int ntiles = nrows >> 4;
    for (int tile = blockIdx.x * 4 + wave; tile < ntiles; tile += gridDim.x * 4) {
        f4v acc[8];
        mfma_tile(X, tile * 16, lds, acc);
#pragma unroll
        for (int t = 0; t < 8; ++t) {
            int col = t * 16 + l15;
#pragma unroll
            for (int r = 0; r < 4; ++r)
                P[(size_t)(tile * 16 + q * 4 + r) * D + col] = acc[t][r];
        }
    }
}

// Per-edge: msg = edge@We2e^T + Ps[sidx] + Pt[tidx]; e_out = edge + LN(silu(msg)).
// Pure streaming: no atomics.
__global__ __launch_bounds__(256) void k_edge(const float* __restrict__ edge,
                                              const int* __restrict__ sidx,
                                              const int* __restrict__ tidx,
                                              const float* __restrict__ W,
                                              const float* __restrict__ Ps,
                                              const float* __restrict__ Pt,
                                              const float* __restrict__ g1,
                                              const float* __restrict__ b1,
                                              float* __restrict__ eout, int E) {
    __shared__ short lds[D * LDSPAD];
    load_w_lds(W, lds);
    __syncthreads();
    const int lane = threadIdx.x & 63, wave = threadIdx.x >> 6;
    const int l15 = lane & 15, q = lane >> 4;
    const int ntiles = E >> 4;
    for (int tile = blockIdx.x * 4 + wave; tile < ntiles; tile += gridDim.x * 4) {
        const int e0 = tile * 16;
        f4v acc[8];
        mfma_tile(edge, e0, lds, acc);
        int si[4], ti[4];
#pragma unroll
        for (int r = 0; r < 4; ++r) {
            si[r] = sidx[e0 + q * 4 + r];
            ti[r] = tidx[e0 + q * 4 + r];
        }
        float h[8][4];
        float s1[4] = {0.f, 0.f, 0.f, 0.f}, s2[4] = {0.f, 0.f, 0.f, 0.f};
#pragma unroll
        for (int t = 0; t < 8; ++t) {
            int col = t * 16 + l15;
#pragma unroll
            for (int r = 0; r < 4; ++r) {
                float m = acc[t][r] + Ps[(size_t)si[r] * D + col]
                                    + Pt[(size_t)ti[r] * D + col];
                float hh = m / (1.f + __expf(-m));   // silu
                h[t][r] = hh;
                s1[r] += hh;
                s2[r] += hh * hh;
            }
        }
#pragma unroll
        for (int m = 1; m < 16; m <<= 1) {
#pragma unroll
            for (int r = 0; r < 4; ++r) {
                s1[r] += __shfl_xor(s1[r], m, 64);
                s2[r] += __shfl_xor(s2[r], m, 64);
            }
        }
        float mean[4], rstd[4];
#pragma unroll
        for (int r = 0; r < 4; ++r) {
            float mu = s1[r] * (1.f / 128.f);
            float var = s2[r] * (1.f / 128.f) - mu * mu;
            mean[r] = mu;
            rstd[r] = rsqrtf(var + 1e-5f);
        }
#pragma unroll
        for (int t = 0; t < 8; ++t) {
            int col = t * 16 + l15;
            float gg = g1[col], bb = b1[col];
#pragma unroll
            for (int r = 0; r < 4; ++r) {
                int rowg = e0 + q * 4 + r;
                float v = edge[(size_t)rowg * D + col]
                          + ((h[t][r] - mean[r]) * rstd[r] * gg + bb);
                eout[(size_t)rowg * D + col] = v;
            }
        }
    }
}

// agg[n] = sum of eout rows for edges targeting n. One wave per node.
__global__ __launch_bounds__(256) void k_agg(const float* __restrict__ eout,
                                             const int* __restrict__ off,
                                             const int* __restrict__ elist,
                                             float* __restrict__ agg, int N) {
    const int node = blockIdx.x * 4 + (threadIdx.x >> 6);
    const int lane = threadIdx.x & 63;
    if (node >= N) return;
    const int lo = off[node], hi = off[node + 1];
    float ax = 0.f, ay = 0.f;
    for (int j = lo; j < hi; ++j) {
        int e = elist[j];
        float2 v = *reinterpret_cast<const float2*>(&eout[(size_t)e * D + 2 * lane]);
        ax += v.x; ay += v.y;
    }
    float2 o = {ax, ay};
    *reinterpret_cast<float2*>(&agg[(size_t)node * D + 2 * lane]) = o;
}

// tgt_msg = agg@We2t^T + Ptt; tgt_out = tgt + LN(silu(tgt_msg)).
// out == aggIn (in-place): each wave reads its 16 rows fully before writing.
__global__ __launch_bounds__(256) void k_node_update(const float* __restrict__ aggIn,
                                                     const float* __restrict__ W,
                                                     const float* __restrict__ Ptt,
                                                     const float* __restrict__ tgt,
                                                     const float* __restrict__ g2,
                                                     const float* __restrict__ b2,
                                                     float* __restrict__ out, int N) {
    __shared__ short lds[D * LDSPAD];
    load_w_lds(W, lds);
    __syncthreads();
    const int lane = threadIdx.x & 63, wave = threadIdx.x >> 6;
    const int l15 = lane & 15, q = lane >> 4;
    const int ntiles = N >> 4;
    for (int tile = blockIdx.x * 4 + wave; tile < ntiles; tile += gridDim.x * 4) {
        const int n0 = tile * 16;
        f4v acc[8];
        mfma_tile(aggIn, n0, lds, acc);
        float h[8][4];
        float s1[4] = {0.f, 0.f, 0.f, 0.f}, s2[4] = {0.f, 0.f, 0.f, 0.f};
#pragma unroll
        for (int t = 0; t < 8; ++t) {
            int col = t * 16 + l15;
#pragma unroll
            for (int r = 0; r < 4; ++r) {
                int rowg = n0 + q * 4 + r;
                float m = acc[t][r] + Ptt[(size_t)rowg * D + col];
                float hh = m / (1.f + __expf(-m));
                h[t][r] = hh;
                s1[r] += hh;
                s2[r] += hh * hh;
            }
        }
#pragma unroll
        for (int m = 1; m < 16; m <<= 1) {
#pragma unroll
            for (int r = 0; r < 4; ++r) {
                s1[r] += __shfl_xor(s1[r], m, 64);
                s2[r] += __shfl_xor(s2[r], m, 64);
            }
        }
        float mean[4], rstd[4];
#pragma unroll
        for (int r = 0; r < 4; ++r) {
            float mu = s1[r] * (1.f / 128.f);
            float var = s2[r] * (1.f / 128.f) - mu * mu;
            mean[r] = mu;
            rstd[r] = rsqrtf(var + 1e-5f);
        }
#pragma unroll
        for (int t = 0; t < 8; ++t) {
            int col = t * 16 + l15;
            float gg = g2[col], bb = b2[col];
#pragma unroll
            for (int r = 0; r < 4; ++r) {
                int rowg = n0 + q * 4 + r;
                float v = tgt[(size_t)rowg * D + col]
                          + ((h[t][r] - mean[r]) * rstd[r] * gg + bb);
                out[(size_t)rowg * D + col] = v;
            }
        }
    }
}

extern "C" void kernel_launch(void* const* d_in, const int* in_sizes, int n_in,
                              void* d_out, int out_size, void* d_ws, size_t ws_size,
                              hipStream_t stream) {
    const float* src   = (const float*)d_in[0];
    const float* tgt   = (const float*)d_in[1];
    const float* edge  = (const float*)d_in[2];
    const int*   sidx  = (const int*)d_in[3];
    const int*   tidx  = (const int*)d_in[4];
    const float* W_s2e = (const float*)d_in[5];
    const float* W_t2e = (const float*)d_in[6];
    const float* W_e2e = (const float*)d_in[7];
    const float* W_e2t = (const float*)d_in[8];
    const float* W_t2t = (const float*)d_in[9];
    const float* g1    = (const float*)d_in[10];
    const float* b1    = (const float*)d_in[11];
    const float* g2    = (const float*)d_in[12];
    const float* b2    = (const float*)d_in[13];

    const int N = in_sizes[0] / D;   // 50000
    const int E = in_sizes[3];       // 500000

    float* eout = (float*)d_out;                    // [E,128]
    float* nout = eout + (size_t)E * D;             // [N,128]: agg, then tgt_out in place

    float* Ps  = (float*)d_ws;                      // [N,128] f32
    float* Pt  = Ps + (size_t)N * D;
    float* Ptt = Pt + (size_t)N * D;
    int*   cnt    = (int*)(Ptt + (size_t)N * D);    // [N]
    int*   off    = cnt + N;                        // [N+1]
    int*   cursor = off + N + 1;                    // [N]
    int*   elist  = cursor + N;                     // [E]

    // ---- CSR build (int atomics only) ----
    k_zero_i<<<(N + 255) / 256, 256, 0, stream>>>(cnt, N);
    k_hist<<<(E + 255) / 256, 256, 0, stream>>>(tidx, cnt, E);
    k_scan<<<1, 1024, 0, stream>>>(cnt, off, cursor, N);
    k_scatter<<<(E + 255) / 256, 256, 0, stream>>>(tidx, cursor, elist, E);

    // ---- node-side transforms ----
    const int nodeBlocks = (N / 16 + 3) / 4;        // one 16-row tile per wave
    k_node_gemm<<<nodeBlocks, 256, 0, stream>>>(src, W_s2e, Ps, N);
    k_node_gemm<<<nodeBlocks, 256, 0, stream>>>(tgt, W_t2e, Pt, N);
    k_node_gemm<<<nodeBlocks, 256, 0, stream>>>(tgt, W_t2t, Ptt, N);

    // ---- edge update (streaming) ----
    k_edge<<<1024, 256, 0, stream>>>(edge, sidx, tidx, W_e2e, Ps, Pt, g1, b1,
                                     eout, E);

    // ---- deterministic aggregation + node update ----
    k_agg<<<(N + 3) / 4, 256, 0, stream>>>(eout, off, elist, nout, N);
    k_node_update<<<nodeBlocks, 256, 0, stream>>>(nout, W_e2t, Ptt, tgt, g2, b2,
                                                  nout, N);
}